// Round 4
// baseline (226.786 us; speedup 1.0000x reference)
//
#include <hip/hip_runtime.h>
#include <hip/hip_bf16.h>

#define Dc   192
#define D2c  384
#define NYc  2304   // 48*48

// 1/sqrt(192) * log2(e): folded into wq weights+bias so QK^T scores are in
// log2 domain and softmax uses raw v_exp_f32 (= 2^x).
#define QSCALE 0.1041175462f

typedef __attribute__((ext_vector_type(8))) short short8;
typedef __attribute__((ext_vector_type(4))) float f32x4;

__device__ __forceinline__ unsigned short f2bf(float f) {
    unsigned int u = __float_as_uint(f);
    u += 0x7FFFu + ((u >> 16) & 1u);   // RNE
    return (unsigned short)(u >> 16);
}
__device__ __forceinline__ float fexp2(float x) {
    float r; asm("v_exp_f32 %0, %1" : "=v"(r) : "v"(x)); return r;
}
__device__ __forceinline__ unsigned cvtpk(float lo, float hi) {
    unsigned r; asm("v_cvt_pk_bf16_f32 %0, %1, %2" : "=v"(r) : "v"(lo), "v"(hi));
    return r;
}

// ---------------------------------------------------------------------------
// pe2d tables: peY[c][p] (384x48), peS[c][p] (192x48); pos-dependence only.
// ---------------------------------------------------------------------------
__global__ __launch_bounds__(256)
void build_pe_kernel(float* __restrict__ peY, float* __restrict__ peS) {
    int idx = blockIdx.x * 256 + threadIdx.x;    // 27648 total
    int c, p, C; float* dst; int off;
    if (idx < 18432) { c = idx / 48; p = idx % 48; C = 384; dst = peY; off = idx; }
    else { int k = idx - 18432; c = k / 48; p = k % 48; C = 192; dst = peS; off = k; }
    int dh = C >> 1;
    int i = ((c < dh) ? c : c - dh) >> 1;
    float divv = expf((float)(2 * i) * (-9.210340371976184f / (float)dh));
    float ang = (float)p * divv;
    dst[off] = (c & 1) ? cosf(ang) : sinf(ang);
}

// PE add + transpose to token-major bf16 (y and s fused; s also keeps fp32 ch-major)
__global__ __launch_bounds__(256)
void prep_pe_kernel(const float* __restrict__ y, const float* __restrict__ s,
                    const float* __restrict__ peY, const float* __restrict__ peS,
                    unsigned short* __restrict__ ytok, unsigned short* __restrict__ stok,
                    float* __restrict__ sch) {
    int idx = blockIdx.x * 256 + threadIdx.x;    // 2654208 total
    if (idx < 1769472) {
        int n = idx % NYc; int c = (idx / NYc) % D2c; int b = idx / (NYc * D2c);
        int pos = (c < 192) ? (n % 48) : (n / 48);
        float v = y[idx] + peY[c * 48 + pos];
        ytok[(long)b * NYc * D2c + (long)n * D2c + c] = f2bf(v);
    } else {
        int k = idx - 1769472;
        int n = k % NYc; int c = (k / NYc) % Dc; int b = k / (NYc * Dc);
        int pos = (c < 96) ? (n % 48) : (n / 48);
        float v = s[k] + peS[c * 48 + pos];
        sch[k] = v;
        stok[(long)b * NYc * Dc + (long)n * Dc + c] = f2bf(v);
    }
}

// weight conversions: seven 1x1 mats (wq pre-scaled) + qk bias + up_w transpose
__global__ __launch_bounds__(256)
void prep_w_kernel(const float* __restrict__ w0, const float* __restrict__ w1,
                   const float* __restrict__ w2, const float* __restrict__ w3,
                   const float* __restrict__ w4, const float* __restrict__ w5,
                   const float* __restrict__ w6, unsigned short* __restrict__ dst,
                   const float* __restrict__ wq_b, const float* __restrict__ wk_b,
                   float* __restrict__ qkb,
                   const float* __restrict__ upw, unsigned short* __restrict__ upwt) {
    int idx = blockIdx.x * 256 + threadIdx.x;    // 1953792 total
    if (idx < 626688) {
        if (idx < 768)
            qkb[idx] = (idx < 384) ? wq_b[idx] * QSCALE : wk_b[idx - 384];
        const float* src; int off; float scl = 1.0f;
        if      (idx < 147456) { src = w0; off = idx; }
        else if (idx < 294912) { src = w1; off = idx - 147456; scl = QSCALE; }
        else if (idx < 442368) { src = w2; off = idx - 294912; }
        else if (idx < 479232) { src = w3; off = idx - 442368; }
        else if (idx < 516096) { src = w4; off = idx - 479232; }
        else if (idx < 552960) { src = w5; off = idx - 516096; }
        else                   { src = w6; off = idx - 552960; }
        dst[idx] = f2bf(src[off] * scl);
    } else {
        int k = idx - 626688;                    // up_w: [O][tap*384+c]
        int o = k / 3456; int r = k % 3456;
        int tap = r / 384;  int c = r % 384;
        upwt[k] = f2bf(upw[((long)o * 384 + c) * 9 + tap]);
    }
}

// ---------------------------------------------------------------------------
// bf16 MFMA GEMM with register-prefetch pipeline.
// D[m][n] = sum_k A'[m][k] * B'[n][k] (+ epilogue); A',B' row-major [free][k].
// Block tile BMt x BNt (128x64 or 64x128), 4 waves, BK=64.
//  BMt=128: waves 2x2, each 64x32 (4x2 frags).  BMt=64: each 32x64 (2x4).
// IM2COL (BMt=128 only): A rows are im2col rows of token-major [4608][384].
// CH_M: bias/bn channel axis is m (weights-as-A) else n.
// ---------------------------------------------------------------------------
enum { E_BIAS = 0, E_BNRELU = 1, E_BNRELU_F32 = 2, E_SIG_F32 = 3 };

template<int EPI, bool IM2COL, bool CH_M, int BMt, int BNt>
__global__ __launch_bounds__(256)
void mfma_gemm(const unsigned short* __restrict__ Ar, long aBatch, int aPitch,
               const unsigned short* __restrict__ Br, long bBatch, int bPitch,
               int K,
               const float* __restrict__ bias, const float* __restrict__ bng,
               const float* __restrict__ bnb,
               const float* __restrict__ smul, long smulBatch,
               void* __restrict__ outv, long oBatch, int oPitch)
{
    constexpr int MF = BMt / 32;      // m fragments per wave
    constexpr int NF = BNt / 32;      // n fragments per wave
    constexpr int LA = BMt / 32;      // staging uint4 per thread (A)
    constexpr int LB = BNt / 32;      // staging uint4 per thread (B)

    int b = blockIdx.z;
    const unsigned short* A = Ar + (long)b * aBatch;
    const unsigned short* B = Br + (long)b * bBatch;
    int m0 = blockIdx.x * BMt, n0 = blockIdx.y * BNt;

    __shared__ __align__(16) unsigned short As[BMt][72];
    __shared__ __align__(16) unsigned short Bs[BNt][72];

    int t = threadIdx.x, lane = t & 63, w = t >> 6;
    int lr = lane & 15, lg = lane >> 4;
    int wm = (BMt == 128) ? (w >> 1) * 64 : (w & 1) * 32;
    int wn = (BNt == 128) ? (w >> 1) * 64 : (w & 1) * 32;

    f32x4 acc[MF][NF];
    #pragma unroll
    for (int i = 0; i < MF; ++i)
        #pragma unroll
        for (int j = 0; j < NF; ++j)
            acc[i][j] = (f32x4){0.f, 0.f, 0.f, 0.f};

    uint4 ra[LA], rb[LB];

    auto load = [&](int k0) {
        #pragma unroll
        for (int i = 0; i < LA; ++i) {
            int idx = t + i * 256, row = idx >> 3, sl = idx & 7;
            if (!IM2COL) {
                ra[i] = *(const uint4*)(A + (long)(m0 + row) * aPitch + k0 + sl * 8);
            } else {
                int tok = m0 + row;
                int bb = (tok >= NYc) ? 1 : 0;
                int n = tok - bb * NYc;
                int tap = k0 / 384;                    // uniform within BK=64 chunk
                int rem = k0 - tap * 384 + sl * 8;
                int py = n / 48 + tap / 3 - 1;
                int px = n % 48 + tap % 3 - 1;
                ra[i] = (py >= 0 && py < 48 && px >= 0 && px < 48)
                    ? *(const uint4*)(A + ((long)bb * NYc + py * 48 + px) * aPitch + rem)
                    : make_uint4(0, 0, 0, 0);
            }
        }
        #pragma unroll
        for (int i = 0; i < LB; ++i) {
            int idx = t + i * 256, row = idx >> 3, sl = idx & 7;
            rb[i] = *(const uint4*)(B + (long)(n0 + row) * bPitch + k0 + sl * 8);
        }
    };
    auto store = [&]() {
        #pragma unroll
        for (int i = 0; i < LA; ++i) {
            int idx = t + i * 256;
            *(uint4*)&As[idx >> 3][(idx & 7) * 8] = ra[i];
        }
        #pragma unroll
        for (int i = 0; i < LB; ++i) {
            int idx = t + i * 256;
            *(uint4*)&Bs[idx >> 3][(idx & 7) * 8] = rb[i];
        }
    };

    load(0); store(); __syncthreads();

    int NT = K / 64;
    for (int tt = 0; tt < NT; ++tt) {
        if (tt + 1 < NT) load((tt + 1) * 64);     // prefetch next tile to regs
        #pragma unroll
        for (int kk = 0; kk < 2; ++kk) {
            short8 af[MF], bf[NF];
            #pragma unroll
            for (int i = 0; i < MF; ++i)
                af[i] = *(const short8*)&As[wm + i * 16 + lr][kk * 32 + lg * 8];
            #pragma unroll
            for (int j = 0; j < NF; ++j)
                bf[j] = *(const short8*)&Bs[wn + j * 16 + lr][kk * 32 + lg * 8];
            #pragma unroll
            for (int i = 0; i < MF; ++i)
                #pragma unroll
                for (int j = 0; j < NF; ++j)
                    acc[i][j] = __builtin_amdgcn_mfma_f32_16x16x32_bf16(
                                    af[i], bf[j], acc[i][j], 0, 0, 0);
        }
        __syncthreads();
        if (tt + 1 < NT) { store(); __syncthreads(); }
    }

    float* outF = (float*)outv;
    unsigned short* outH = (unsigned short*)outv;
    long ob = (long)b * oBatch;
    #pragma unroll
    for (int i = 0; i < MF; ++i)
    #pragma unroll
    for (int j = 0; j < NF; ++j)
    #pragma unroll
    for (int r = 0; r < 4; ++r) {
        int gm = m0 + wm + i * 16 + lg * 4 + r;
        int gn = n0 + wn + j * 16 + lr;
        int ch = CH_M ? gm : gn;
        float v = acc[i][j][r] + bias[ch];
        if (EPI == E_BNRELU || EPI == E_BNRELU_F32)
            v = fmaxf(fmaf(v, bng[ch], bnb[ch]), 0.f);
        if (EPI == E_SIG_F32) {
            v = fmaf(v, bng[ch], bnb[ch]);
            v = 1.f / (1.f + __expf(-v));
            v *= smul[(long)b * smulBatch + (long)gm * NYc + gn];
        }
        long o = ob + (long)gm * oPitch + gn;
        if (EPI == E_BNRELU_F32 || EPI == E_SIG_F32) outF[o] = v;
        else                                         outH[o] = f2bf(v);
    }
}

// ---------------------------------------------------------------------------
// Fused MFMA flash attention (unchanged from round 3 — passing, ~33 us).
// ---------------------------------------------------------------------------
__global__ __launch_bounds__(512)
void attn_kernel(const unsigned short* __restrict__ QK,
                 const unsigned short* __restrict__ Vc,
                 unsigned short* __restrict__ Zt)
{
    int qb = blockIdx.x;                 // 0..35
    int bh = blockIdx.y;                 // 0..15
    int b = bh >> 3, h = bh & 7;
    const unsigned short* Qg = QK + (long)b * NYc * 768 + h * 48;
    const unsigned short* Kg = Qg + 384;
    const unsigned short* Vg = Vc + ((long)b * Dc + h * 24) * NYc;
    unsigned short*       Z  = Zt + (long)b * NYc * Dc + h * 24;

    __shared__ __align__(16) unsigned short Ks_[128][72];
    __shared__ __align__(16) unsigned short Vs_[32][136];
    __shared__ __align__(16) unsigned int   Ps_[8][16][36];

    int t = threadIdx.x, lane = t & 63, w = t >> 6;
    int lr = lane & 15, lg = lane >> 4;
    int tm = w >> 1, hf = w & 1;
    int q0 = qb * 64;

    short8 z8 = {0, 0, 0, 0, 0, 0, 0, 0};
    const unsigned short* qrow = Qg + (long)(q0 + tm * 16 + lr) * 768;
    short8 bq0 = *(const short8*)(qrow + lg * 8);
    short8 bq1 = (lg < 2) ? *(const short8*)(qrow + 32 + lg * 8) : z8;

    float m_run = -1e30f, l_run = 0.f;
    f32x4 O0 = {0.f, 0.f, 0.f, 0.f}, O1 = {0.f, 0.f, 0.f, 0.f};

    for (int kt = 0; kt < 18; ++kt) {
        long k0 = kt * 128;
        #pragma unroll
        for (int i = 0; i < 2; ++i) {           // K tile: 128 rows x 8 slots
            int idx = t + i * 512;
            int row = idx >> 3, sl = idx & 7;
            uint4 v = make_uint4(0, 0, 0, 0);
            if (sl < 6) v = *(const uint4*)(Kg + (k0 + row) * 768 + sl * 8);
            *(uint4*)&Ks_[row][sl * 8] = v;
        }
        if (t < 384) {                          // V tile: 24 rows x 16 slots
            int row = t >> 4, sl = t & 15;
            *(uint4*)&Vs_[row][sl * 8] =
                *(const uint4*)(Vg + (long)row * NYc + k0 + sl * 8);
        }
        __syncthreads();

        f32x4 sS[4];
        #pragma unroll
        for (int ks = 0; ks < 4; ++ks) {
            short8 ak0 = *(const short8*)&Ks_[hf * 64 + ks * 16 + lr][lg * 8];
            short8 ak1 = *(const short8*)&Ks_[hf * 64 + ks * 16 + lr][32 + lg * 8];
            f32x4 c = {0.f, 0.f, 0.f, 0.f};
            c = __builtin_amdgcn_mfma_f32_16x16x32_bf16(ak0, bq0, c, 0, 0, 0);
            c = __builtin_amdgcn_mfma_f32_16x16x32_bf16(ak1, bq1, c, 0, 0, 0);
            sS[ks] = c;
        }

        float tmax = -1e30f;
        #pragma unroll
        for (int ks = 0; ks < 4; ++ks)
            #pragma unroll
            for (int r = 0; r < 4; ++r) tmax = fmaxf(tmax, sS[ks][r]);
        tmax = fmaxf(tmax, __shfl_xor(tmax, 16));
        tmax = fmaxf(tmax, __shfl_xor(tmax, 32));

        if (__any(tmax > m_run + 10.f)) {
            float mn = fmaxf(m_run, tmax);
            float al = fexp2(m_run - mn);
            m_run = mn;
            l_run *= al;
            #pragma unroll
            for (int rr = 0; rr < 4; ++rr) {
                float arr = __shfl(al, (lane & 48) | (lg * 4 + rr));
                O0[rr] *= arr; O1[rr] *= arr;
            }
        }

        float psum = 0.f;
        #pragma unroll
        for (int ks = 0; ks < 4; ++ks) {
            float p0 = fexp2(sS[ks][0] - m_run);
            float p1 = fexp2(sS[ks][1] - m_run);
            float p2 = fexp2(sS[ks][2] - m_run);
            float p3 = fexp2(sS[ks][3] - m_run);
            psum += (p0 + p1) + (p2 + p3);
            Ps_[w][lr][8 * ks + 2 * lg]     = cvtpk(p0, p1);
            Ps_[w][lr][8 * ks + 2 * lg + 1] = cvtpk(p2, p3);
        }
        psum += __shfl_xor(psum, 16);
        psum += __shfl_xor(psum, 32);
        l_run += psum;

        short8 ap0 = *(const short8*)&Ps_[w][lr][4 * lg];
        short8 ap1 = *(const short8*)&Ps_[w][lr][16 + 4 * lg];
        short8 bv00 = *(const short8*)&Vs_[lr][hf * 64 + lg * 8];
        short8 bv01 = *(const short8*)&Vs_[lr][hf * 64 + 32 + lg * 8];
        short8 bv10 = *(const short8*)&Vs_[16 + lr][hf * 64 + lg * 8];
        short8 bv11 = *(const short8*)&Vs_[16 + lr][hf * 64 + 32 + lg * 8];
        O0 = __builtin_amdgcn_mfma_f32_16x16x32_bf16(ap0, bv00, O0, 0, 0, 0);
        O0 = __builtin_amdgcn_mfma_f32_16x16x32_bf16(ap1, bv01, O0, 0, 0, 0);
        O1 = __builtin_amdgcn_mfma_f32_16x16x32_bf16(ap0, bv10, O1, 0, 0, 0);
        O1 = __builtin_amdgcn_mfma_f32_16x16x32_bf16(ap1, bv11, O1, 0, 0, 0);
        __syncthreads();
    }

    float* Cf = (float*)&Ps_[0][0][0];
    float* T = Cf + tm * 576;
    if (hf == 1) {
        #pragma unroll
        for (int j = 0; j < 4; ++j) {
            T[lane * 8 + j]     = O0[j];
            T[lane * 8 + 4 + j] = O1[j];
        }
        if (lane < 16) { T[512 + lane] = m_run; T[528 + lane] = l_run; }
    }
    __syncthreads();
    if (hf == 0) {
        float mB = T[512 + lr], lB = T[528 + lr];
        float mS = fmaxf(m_run, mB);
        float aA = fexp2(m_run - mS), aB = fexp2(mB - mS);
        float invl = 1.f / (l_run * aA + lB * aB);
        float fA = aA * invl, fB = aB * invl;
        #pragma unroll
        for (int rr = 0; rr < 4; ++rr) {
            int src = (lane & 48) | (lg * 4 + rr);
            float gA = __shfl(fA, src), gB = __shfl(fB, src);
            int n = q0 + tm * 16 + lg * 4 + rr;
            unsigned short* zr = Z + (long)n * Dc;
            float z0 = O0[rr] * gA + T[lane * 8 + rr] * gB;
            zr[lr] = f2bf(z0);
            if (lr < 8) {
                float z1 = O1[rr] * gA + T[lane * 8 + 4 + rr] * gB;
                zr[16 + lr] = f2bf(z1);
            }
        }
    }
}

// ---------------------------------------------------------------------------
extern "C" void kernel_launch(void* const* d_in, const int* in_sizes, int n_in,
                              void* d_out, int out_size, void* d_ws, size_t ws_size,
                              hipStream_t stream) {
    const float* y       = (const float*)d_in[0];
    const float* s       = (const float*)d_in[1];
    const float* wq_w    = (const float*)d_in[2];
    const float* wq_b    = (const float*)d_in[3];
    const float* wk_w    = (const float*)d_in[4];
    const float* wk_b    = (const float*)d_in[5];
    const float* wv_w    = (const float*)d_in[6];
    const float* wv_b    = (const float*)d_in[7];
    const float* conv1_w = (const float*)d_in[8];
    const float* conv1_b = (const float*)d_in[9];
    const float* bn1_g   = (const float*)d_in[10];
    const float* bn1_b   = (const float*)d_in[11];
    const float* conv2_w = (const float*)d_in[12];
    const float* conv2_b = (const float*)d_in[13];
    const float* bn2_g   = (const float*)d_in[14];
    const float* bn2_b   = (const float*)d_in[15];
    const float* up_w    = (const float*)d_in[16];
    const float* up_b    = (const float*)d_in[17];
    const float* conv3_w = (const float*)d_in[18];
    const float* conv3_b = (const float*)d_in[19];
    const float* bn3_g   = (const float*)d_in[20];
    const float* bn3_b   = (const float*)d_in[21];
    const float* sig_w   = (const float*)d_in[22];
    const float* sig_b   = (const float*)d_in[23];
    const float* bnsig_g = (const float*)d_in[24];
    const float* bnsig_b = (const float*)d_in[25];

    unsigned short* wsp   = (unsigned short*)d_ws;
    unsigned short* wcvt  = wsp;                     // 626688
    unsigned short* upwt  = wcvt + 626688;           // 1327104
    unsigned short* y_pe  = upwt + 1327104;          // 1769472  [4608][384]
    unsigned short* s_pe  = y_pe + 1769472;          //  884736  [4608][192]
    unsigned short* y_c1  = s_pe + 884736;           // 1769472
    unsigned short* s_c2  = y_c1 + 1769472;          //  884736
    unsigned short* y_up  = s_c2 + 884736;           // 1769472
    unsigned short* QKtok = y_up + 1769472;          // 3538944  [b][n][768]
    unsigned short* Vch   = QKtok + 3538944;         //  884736
    unsigned short* Ztok  = Vch + 884736;            //  884736
    float*          s_ch  = (float*)(Ztok + 884736); //  884736 fp32
    float*          qkb   = s_ch + 884736;           //  768 fp32
    float*          peY   = qkb + 768;               //  18432 fp32
    float*          peS   = peY + 18432;             //  9216 fp32

    const unsigned short* conv1wb = wcvt;
    const unsigned short* wqkb    = wcvt + 147456;   // wq||wk, 768 x 384
    const unsigned short* conv2wb = wcvt + 442368;
    const unsigned short* wvb     = wcvt + 479232;
    const unsigned short* sigwb   = wcvt + 516096;
    const unsigned short* conv3wb = wcvt + 552960;

    const long SY2 = (long)D2c * NYc;   // 884736
    const long SY1 = (long)Dc * NYc;    // 442368

    build_pe_kernel<<<108, 256, 0, stream>>>(peY, peS);
    prep_pe_kernel<<<10368, 256, 0, stream>>>(y, s, peY, peS, y_pe, s_pe, s_ch);
    prep_w_kernel<<<7632, 256, 0, stream>>>(conv1_w, wq_w, wk_w, conv2_w,
                                            wv_w, sig_w, conv3_w, wcvt,
                                            wq_b, wk_b, qkb, up_w, upwt);

    dim3 blk(256);
    // conv1: y_pe [4608][384] x conv1_w -> y_c1 [4608][384], BN+ReLU
    mfma_gemm<E_BNRELU, false, false, 128, 64><<<dim3(36, 6, 1), blk, 0, stream>>>(
        y_pe, 0, D2c, conv1wb, 0, D2c, D2c,
        conv1_b, bn1_g, bn1_b, nullptr, 0, y_c1, 0, D2c);
    // conv2: s_pe [4608][192] x conv2_w -> s_c2, BN+ReLU
    mfma_gemm<E_BNRELU, false, false, 128, 64><<<dim3(36, 3, 1), blk, 0, stream>>>(
        s_pe, 0, Dc, conv2wb, 0, Dc, Dc,
        conv2_b, bn2_g, bn2_b, nullptr, 0, s_c2, 0, Dc);
    // up: im2col 3x3, y_pe x up_wt [384][3456] -> y_up [4608][384], bias
    mfma_gemm<E_BIAS, true, false, 128, 64><<<dim3(36, 6, 1), blk, 0, stream>>>(
        y_pe, 0, D2c, upwt, 0, 9 * D2c, 9 * D2c,
        up_b, nullptr, nullptr, nullptr, 0, y_up, 0, D2c);
    // conv3: conv3_w x y_up -> d_out[192:384) fp32 ch-major, BN+ReLU
    mfma_gemm<E_BNRELU_F32, false, true, 64, 128><<<dim3(3, 18, 2), blk, 0, stream>>>(
        conv3wb, 0, D2c, y_up, SY2, D2c, D2c,
        conv3_b, bn3_g, bn3_b, nullptr, 0,
        (float*)d_out + (long)Dc * NYc, SY2, NYc);
    // fused Q+K projection: y_c1 x (wq||wk) -> QKtok [4608][768]
    mfma_gemm<E_BIAS, false, false, 128, 64><<<dim3(36, 12, 1), blk, 0, stream>>>(
        y_c1, 0, D2c, wqkb, 0, D2c, D2c,
        qkb, nullptr, nullptr, nullptr, 0, QKtok, 0, 768);
    // V: wv x s_c2 -> V_ch [b][192][2304]
    mfma_gemm<E_BIAS, false, true, 64, 128><<<dim3(3, 18, 2), blk, 0, stream>>>(
        wvb, 0, Dc, s_c2, SY1, Dc, Dc,
        wv_b, nullptr, nullptr, nullptr, 0, Vch, SY1, NYc);
    // attention
    attn_kernel<<<dim3(36, 16), dim3(512), 0, stream>>>(QKtok, Vch, Ztok);
    // sigmoid gate: sig_w x Ztok -> sigmoid(bn(.)) * s_pe -> d_out[0:192) fp32
    mfma_gemm<E_SIG_F32, false, true, 64, 128><<<dim3(3, 18, 2), blk, 0, stream>>>(
        sigwb, 0, Dc, Ztok, SY1, Dc, Dc,
        sig_b, bnsig_g, bnsig_b, s_ch, SY1,
        (float*)d_out, SY2, NYc);
}